// Round 5
// baseline (907.160 us; speedup 1.0000x reference)
//
#include <hip/hip_runtime.h>
#include <math.h>

// Problem constants (fixed by the reference)
constexpr int kT = 500000;     // history length
constexpr int kQ = 256;        // feature size
constexpr int kH = 256;        // hidden size
constexpr int kK = 32;         // attn_k
constexpr int kNB1 = 256;      // phase-1 top-k blocks
constexpr int kCHUNK = (kT + kNB1 - 1) / kNB1;  // 1954
constexpr int kNC = kNB1 * kK; // 8192 merge candidates
constexpr int kGruRows = 3 * kH;              // 768
constexpr int kGruBlocks = kGruRows / 4;      // 192 (4 waves/block, 1 row/wave)

typedef float f4 __attribute__((ext_vector_type(4)));

__device__ __forceinline__ float dot4(f4 a, f4 b) {
  return a.x * b.x + a.y * b.y + a.z * b.z + a.w * b.w;
}

// Scratch floats: alpha kT | candV kNC | candI kNC | gi 768 | gh 768
constexpr size_t kScratchFloats = (size_t)kT + 2 * kNC + 2 * kGruRows;

// ---------------------------------------------------------------------------
// Read-only alpha matvec: alpha[t] = qs[t] . qh. One wave per row.
__global__ __launch_bounds__(256) void k_alpha(
    const float* __restrict__ qs, const float* __restrict__ qh,
    float* __restrict__ alpha) {
  const int lane = threadIdx.x & 63;
  const int wid  = (int)((blockIdx.x * blockDim.x + threadIdx.x) >> 6);
  const int nw   = (int)((gridDim.x * blockDim.x) >> 6);
  const f4 q4 = ((const f4*)qh)[lane];
  for (int t = wid; t < kT; t += nw) {
    f4 v = ((const f4*)(qs + (size_t)t * kQ))[lane];
    float d = dot4(v, q4);
#pragma unroll
    for (int off = 32; off; off >>= 1) d += __shfl_xor(d, off);
    if (lane == 0) alpha[t] = d;
  }
}

// ---------------------------------------------------------------------------
// GRU matvecs: one row per wave, 4 waves/block.
__global__ __launch_bounds__(256) void k_gru1(
    const float* __restrict__ Wih, const float* __restrict__ Whh,
    const float* __restrict__ bih, const float* __restrict__ bhh,
    const float* __restrict__ qh, const float* __restrict__ hs,
    const float* __restrict__ score, float* __restrict__ gi,
    float* __restrict__ gh) {
  const int lane = threadIdx.x & 63;
  const int r = blockIdx.x * 4 + (threadIdx.x >> 6);
  const int off = (score[0] >= 0.5f) ? 0 : kQ;  // x = [qh*ge, qh*(1-ge)]
  const float* hprev = hs + (size_t)(kT - 1) * kH;
  f4 q4 = ((const f4*)qh)[lane];
  f4 h4 = ((const f4*)hprev)[lane];
  f4 wi = ((const f4*)(Wih + (size_t)r * (2 * kQ) + off))[lane];
  f4 wh = ((const f4*)(Whh + (size_t)r * kH))[lane];
  float di = dot4(wi, q4);
  float dh = dot4(wh, h4);
#pragma unroll
  for (int o = 32; o; o >>= 1) {
    di += __shfl_xor(di, o);
    dh += __shfl_xor(dh, o);
  }
  if (lane == 0) {
    gi[r] = di + bih[r];
    gh[r] = dh + bhh[r];
  }
}

// Final rows: block 0 = GRU gates -> h_new -> last output row;
//             block 1 = ques_h -> qs_new row kT.
__global__ __launch_bounds__(256) void k_finalrows(
    const float* __restrict__ gi, const float* __restrict__ gh,
    const float* __restrict__ hs, const float* __restrict__ qh,
    float* __restrict__ out) {
  const int i = threadIdx.x;
  if (blockIdx.x == 1) {
    out[1 + (size_t)kT * kQ + i] = qh[i];
    return;
  }
  const float* hprev = hs + (size_t)(kT - 1) * kH;
  float rr = 1.f / (1.f + expf(-(gi[i] + gh[i])));
  float z  = 1.f / (1.f + expf(-(gi[kH + i] + gh[kH + i])));
  float n  = tanhf(gi[2 * kH + i] + rr * gh[2 * kH + i]);
  out[1 + (size_t)(kT + 1) * kQ + (size_t)kT * kH + i] =
      (1.f - z) * n + z * hprev[i];
}

// ---------------------------------------------------------------------------
// Top-k phase 1: each block extracts its chunk's top-32 from LDS.
__global__ __launch_bounds__(256) void k_topk1(
    const float* __restrict__ alpha, float* __restrict__ candV,
    int* __restrict__ candI) {
  __shared__ float sv[kCHUNK];
  __shared__ float rv[4];
  __shared__ int ri[4];
  const int tid = threadIdx.x;
  const int base = blockIdx.x * kCHUNK;
  for (int i = tid; i < kCHUNK; i += 256) {
    int g = base + i;
    sv[i] = (g < kT) ? alpha[g] : -INFINITY;
  }
  __syncthreads();
  for (int k = 0; k < kK; ++k) {
    float bv = -INFINITY; int bi = -1;
    for (int i = tid; i < kCHUNK; i += 256) {
      float v = sv[i];
      if (v > bv) { bv = v; bi = i; }
    }
#pragma unroll
    for (int off = 32; off; off >>= 1) {
      float ov = __shfl_xor(bv, off);
      int   oi = __shfl_xor(bi, off);
      if (ov > bv || (ov == bv && oi != -1 && (bi == -1 || oi < bi))) { bv = ov; bi = oi; }
    }
    if ((tid & 63) == 0) { rv[tid >> 6] = bv; ri[tid >> 6] = bi; }
    __syncthreads();
    if (tid == 0) {
      float fv = rv[0]; int fi = ri[0];
      for (int j = 1; j < 4; ++j)
        if (rv[j] > fv || (rv[j] == fv && ri[j] != -1 && (fi == -1 || ri[j] < fi))) {
          fv = rv[j]; fi = ri[j];
        }
      candV[blockIdx.x * kK + k] = fv;
      candI[blockIdx.x * kK + k] = (fi >= 0) ? (base + fi) : 0;
      if (fi >= 0) sv[fi] = -INFINITY;
    }
    __syncthreads();
  }
}

// Top-k phase 2 + softmax + attention + pred (single block).
__global__ __launch_bounds__(256) void k_attn(
    const float* __restrict__ candV, const int* __restrict__ candI,
    const float* __restrict__ hs, const float* __restrict__ qh,
    const float* __restrict__ Ws, const float* __restrict__ bs,
    float* __restrict__ out) {
  __shared__ float sv[kNC];
  __shared__ float rv[4];
  __shared__ int ri[4];
  __shared__ float topv[kK];
  __shared__ int topi[kK];
  __shared__ float w[kK];
  __shared__ float red[256];
  const int tid = threadIdx.x;
  for (int i = tid; i < kNC; i += 256) sv[i] = candV[i];
  __syncthreads();
  for (int k = 0; k < kK; ++k) {
    float bv = -INFINITY; int bi = -1;
    for (int i = tid; i < kNC; i += 256) {
      float v = sv[i];
      if (v > bv) { bv = v; bi = i; }
    }
#pragma unroll
    for (int off = 32; off; off >>= 1) {
      float ov = __shfl_xor(bv, off);
      int   oi = __shfl_xor(bi, off);
      if (ov > bv || (ov == bv && oi != -1 && (bi == -1 || oi < bi))) { bv = ov; bi = oi; }
    }
    if ((tid & 63) == 0) { rv[tid >> 6] = bv; ri[tid >> 6] = bi; }
    __syncthreads();
    if (tid == 0) {
      float fv = rv[0]; int fi = ri[0];
      for (int j = 1; j < 4; ++j)
        if (rv[j] > fv || (rv[j] == fv && ri[j] != -1 && (fi == -1 || ri[j] < fi))) {
          fv = rv[j]; fi = ri[j];
        }
      topv[k] = fv;
      topi[k] = candI[fi];
      sv[fi] = -INFINITY;
    }
    __syncthreads();
  }
  if (tid == 0) {
    float m = topv[0];
    for (int j = 1; j < kK; ++j) m = fmaxf(m, topv[j]);
    float s = 0.f;
    for (int j = 0; j < kK; ++j) { w[j] = expf(topv[j] - m); s += w[j]; }
    float inv = 1.f / s;
    for (int j = 0; j < kK; ++j) w[j] *= inv;
  }
  __syncthreads();
  float a = 0.f;
#pragma unroll
  for (int j = 0; j < kK; ++j) a += w[j] * hs[(size_t)topi[j] * kH + tid];
  red[tid] = Ws[tid] * qh[tid] + Ws[kQ + tid] * a;
  __syncthreads();
  for (int s = 128; s; s >>= 1) {
    if (tid < s) red[tid] += red[tid + s];
    __syncthreads();
  }
  if (tid == 0) out[0] = red[0] + bs[0];
}

extern "C" void kernel_launch(void* const* d_in, const int* in_sizes, int n_in,
                              void* d_out, int out_size, void* d_ws, size_t ws_size,
                              hipStream_t stream) {
  const float* qh    = (const float*)d_in[0];
  const float* score = (const float*)d_in[1];
  const float* qs    = (const float*)d_in[2];
  const float* hs    = (const float*)d_in[3];
  const float* Wih   = (const float*)d_in[4];
  const float* Whh   = (const float*)d_in[5];
  const float* bih   = (const float*)d_in[6];
  const float* bhh   = (const float*)d_in[7];
  const float* Ws    = (const float*)d_in[8];
  const float* bs    = (const float*)d_in[9];
  float* out = (float*)d_out;

  const bool useWs = ws_size >= kScratchFloats * sizeof(float);
  // Fallback: scratch at start of the hs_new output region; all consumers run
  // before the hs memcpy overwrites it.
  float* S = useWs ? (float*)d_ws : (out + 1 + (size_t)(kT + 1) * kQ);
  float* alpha = S;                         // kT
  float* candV = S + kT;                    // kNC
  int*   candI = (int*)(candV + kNC);       // kNC
  float* gi    = candV + 2 * kNC;           // 768
  float* gh    = gi + kGruRows;             // 768

  // Small compute first (alpha -> topk -> attn; gru -> final rows).
  hipLaunchKernelGGL(k_gru1, dim3(kGruBlocks), dim3(256), 0, stream,
                     Wih, Whh, bih, bhh, qh, hs, score, gi, gh);
  hipLaunchKernelGGL(k_finalrows, dim3(2), dim3(256), 0, stream,
                     gi, gh, hs, qh, out);
  hipLaunchKernelGGL(k_alpha, dim3(2048), dim3(256), 0, stream,
                     qs, qh, alpha);
  hipLaunchKernelGGL(k_topk1, dim3(kNB1), dim3(256), 0, stream,
                     alpha, candV, candI);
  hipLaunchKernelGGL(k_attn, dim3(1), dim3(256), 0, stream,
                     candV, candI, hs, qh, Ws, bs, out);

  // Bulk copies via the runtime's D2D path (allowed in graph capture).
  // qs_new rows [0, kT): out[1 ..] = qs flat.
  hipMemcpyAsync(out + 1, qs, (size_t)kT * kQ * sizeof(float),
                 hipMemcpyDeviceToDevice, stream);
  // hs_new rows [0, kT): overwrites fallback scratch LAST.
  hipMemcpyAsync(out + 1 + (size_t)(kT + 1) * kQ, hs,
                 (size_t)kT * kH * sizeof(float),
                 hipMemcpyDeviceToDevice, stream);
}

// Round 6
// 718.423 us; speedup vs baseline: 1.2627x; 1.2627x over previous
//
#include <hip/hip_runtime.h>
#include <math.h>

// Problem constants (fixed by the reference)
constexpr int kT = 500000;     // history length
constexpr int kQ = 256;        // feature size
constexpr int kH = 256;        // hidden size
constexpr int kK = 32;         // attn_k
constexpr int kNB1 = 256;      // phase-1 top-k blocks
constexpr int kCHUNK = (kT + kNB1 - 1) / kNB1;  // 1954
constexpr int kNC = kNB1 * kK; // 8192 merge candidates
constexpr int kGruRows = 3 * kH;              // 768
constexpr int kGruBlocks = kGruRows / 4;      // 192

// Flat source layout: qs | qh | hs | hnew  (out[1+i] = flat_src[i])
constexpr long long kA = (long long)kT * kQ;        // 128,000,000  qs end
constexpr long long kB = kA + kQ;                   // 128,000,256  qh end
constexpr long long kC = kB + (long long)kT * kH;   // 256,000,256  hs end
constexpr long long kD = kC + kH;                   // 256,000,512  hnew end
// Aligned 16B out-chunks: chunk k covers out[4k..4k+3] = src[4k-1..4k+2].
constexpr long long kEndFast = (kD - 3) / 4;        // 64,000,127 (full copy)
constexpr long long kEndFall = (kC - 3) / 4;        // 64,000,063 (stop at hs end)

typedef float f4 __attribute__((ext_vector_type(4)));
typedef float f4u __attribute__((ext_vector_type(4), aligned(4)));

__device__ __forceinline__ float dot4(f4 a, f4 b) {
  return a.x * b.x + a.y * b.y + a.z * b.z + a.w * b.w;
}

// Scratch floats: alpha kT | candV kNC | candI kNC | gi 768 | gh 768 | hnew 256
constexpr size_t kScratchFloats = (size_t)kT + 2 * kNC + 2 * kGruRows + kH;

// ---------------------------------------------------------------------------
// Pure flat shifted copy. NO VALU work beyond addressing: aligned stores,
// 4B-misaligned vector loads. Thread-per-chunk grid-stride (m13 structure).
__global__ __launch_bounds__(256) void k_copy(
    const float* __restrict__ qs, const float* __restrict__ hs,
    const float* __restrict__ qh, const float* __restrict__ hnew,
    float* __restrict__ out, long long kEnd, int fastTail) {
  const long long i0 = (long long)blockIdx.x * blockDim.x + threadIdx.x;
  const long long stride = (long long)gridDim.x * blockDim.x;
  for (long long k = 1 + i0; k <= kEnd; k += stride) {
    const long long s = 4 * k - 1;
    f4 v;
    if (s >= kB && s + 3 < kC) {              // hs bulk (most chunks)
      v = *(const f4u*)(hs + (s - kB));
    } else if (s + 3 < kA) {                  // qs bulk
      v = *(const f4u*)(qs + s);
    } else {                                  // boundaries (~3 threads) + qh/hnew
      float tmp[4];
#pragma unroll
      for (int e = 0; e < 4; ++e) {
        long long si = s + e;
        float x;
        if (si < kA)      x = qs[si];
        else if (si < kB) x = qh[si - kA];
        else if (si < kC) x = hs[si - kB];
        else              x = hnew[si - kC];
        tmp[e] = x;
      }
      v.x = tmp[0]; v.y = tmp[1]; v.z = tmp[2]; v.w = tmp[3];
    }
    *(f4*)(out + 4 * k) = v;                  // 16B-aligned store
  }
  if (i0 == 0) {
    out[1] = qs[0]; out[2] = qs[1]; out[3] = qs[2];
    if (fastTail) out[kD] = hnew[kH - 1];     // last output float
  }
}

// ---------------------------------------------------------------------------
// Read-only alpha matvec, 4 independent rows per wave-iteration (ILP hides
// the 6-step swizzle-reduce latency; no store stream to fight).
__global__ __launch_bounds__(256) void k_alpha(
    const float* __restrict__ qs, const float* __restrict__ qh,
    float* __restrict__ alpha) {
  const int lane = threadIdx.x & 63;
  const int wid  = (int)((blockIdx.x * blockDim.x + threadIdx.x) >> 6);
  const int nw   = (int)((gridDim.x * blockDim.x) >> 6);
  const f4 q4 = ((const f4*)qh)[lane];
  int t = wid;
  for (; t + 3 * nw < kT; t += 4 * nw) {
    f4 v0 = ((const f4*)(qs + (size_t)t * kQ))[lane];
    f4 v1 = ((const f4*)(qs + (size_t)(t + nw) * kQ))[lane];
    f4 v2 = ((const f4*)(qs + (size_t)(t + 2 * nw) * kQ))[lane];
    f4 v3 = ((const f4*)(qs + (size_t)(t + 3 * nw) * kQ))[lane];
    float d0 = dot4(v0, q4), d1 = dot4(v1, q4);
    float d2 = dot4(v2, q4), d3 = dot4(v3, q4);
#pragma unroll
    for (int off = 32; off; off >>= 1) {
      d0 += __shfl_xor(d0, off);
      d1 += __shfl_xor(d1, off);
      d2 += __shfl_xor(d2, off);
      d3 += __shfl_xor(d3, off);
    }
    if (lane == 0) {
      alpha[t] = d0; alpha[t + nw] = d1;
      alpha[t + 2 * nw] = d2; alpha[t + 3 * nw] = d3;
    }
  }
  for (; t < kT; t += nw) {
    f4 v = ((const f4*)(qs + (size_t)t * kQ))[lane];
    float d = dot4(v, q4);
#pragma unroll
    for (int off = 32; off; off >>= 1) d += __shfl_xor(d, off);
    if (lane == 0) alpha[t] = d;
  }
}

// ---------------------------------------------------------------------------
// GRU matvecs: one row per wave, 4 waves/block.
__global__ __launch_bounds__(256) void k_gru1(
    const float* __restrict__ Wih, const float* __restrict__ Whh,
    const float* __restrict__ bih, const float* __restrict__ bhh,
    const float* __restrict__ qh, const float* __restrict__ hs,
    const float* __restrict__ score, float* __restrict__ gi,
    float* __restrict__ gh) {
  const int lane = threadIdx.x & 63;
  const int r = blockIdx.x * 4 + (threadIdx.x >> 6);
  const int off = (score[0] >= 0.5f) ? 0 : kQ;  // x = [qh*ge, qh*(1-ge)]
  const float* hprev = hs + (size_t)(kT - 1) * kH;
  f4 q4 = ((const f4*)qh)[lane];
  f4 h4 = ((const f4*)hprev)[lane];
  f4 wi = ((const f4*)(Wih + (size_t)r * (2 * kQ) + off))[lane];
  f4 wh = ((const f4*)(Whh + (size_t)r * kH))[lane];
  float di = dot4(wi, q4);
  float dh = dot4(wh, h4);
#pragma unroll
  for (int o = 32; o; o >>= 1) {
    di += __shfl_xor(di, o);
    dh += __shfl_xor(dh, o);
  }
  if (lane == 0) {
    gi[r] = di + bih[r];
    gh[r] = dh + bhh[r];
  }
}

// GRU gates -> hnew_dst. In fallback mode also writes the one hs element the
// capped copy misses (out[kC] = hs last) from thread 0.
__global__ __launch_bounds__(256) void k_gru2(
    const float* __restrict__ gi, const float* __restrict__ gh,
    const float* __restrict__ hs, float* __restrict__ hnew_dst,
    float* __restrict__ out, int fallbackTail) {
  const int i = threadIdx.x;
  const float* hprev = hs + (size_t)(kT - 1) * kH;
  float rr = 1.f / (1.f + expf(-(gi[i] + gh[i])));
  float z  = 1.f / (1.f + expf(-(gi[kH + i] + gh[kH + i])));
  float n  = tanhf(gi[2 * kH + i] + rr * gh[2 * kH + i]);
  hnew_dst[i] = (1.f - z) * n + z * hprev[i];
  if (fallbackTail && i == 0) out[kC] = hs[(size_t)kT * kH - 1];
}

// ---------------------------------------------------------------------------
// Top-k phase 1: each block extracts its chunk's top-32 from LDS.
__global__ __launch_bounds__(256) void k_topk1(
    const float* __restrict__ alpha, float* __restrict__ candV,
    int* __restrict__ candI) {
  __shared__ float sv[kCHUNK];
  __shared__ float rv[4];
  __shared__ int ri[4];
  const int tid = threadIdx.x;
  const int base = blockIdx.x * kCHUNK;
  for (int i = tid; i < kCHUNK; i += 256) {
    int g = base + i;
    sv[i] = (g < kT) ? alpha[g] : -INFINITY;
  }
  __syncthreads();
  for (int k = 0; k < kK; ++k) {
    float bv = -INFINITY; int bi = -1;
    for (int i = tid; i < kCHUNK; i += 256) {
      float v = sv[i];
      if (v > bv) { bv = v; bi = i; }
    }
#pragma unroll
    for (int off = 32; off; off >>= 1) {
      float ov = __shfl_xor(bv, off);
      int   oi = __shfl_xor(bi, off);
      if (ov > bv || (ov == bv && oi != -1 && (bi == -1 || oi < bi))) { bv = ov; bi = oi; }
    }
    if ((tid & 63) == 0) { rv[tid >> 6] = bv; ri[tid >> 6] = bi; }
    __syncthreads();
    if (tid == 0) {
      float fv = rv[0]; int fi = ri[0];
      for (int j = 1; j < 4; ++j)
        if (rv[j] > fv || (rv[j] == fv && ri[j] != -1 && (fi == -1 || ri[j] < fi))) {
          fv = rv[j]; fi = ri[j];
        }
      candV[blockIdx.x * kK + k] = fv;
      candI[blockIdx.x * kK + k] = (fi >= 0) ? (base + fi) : 0;
      if (fi >= 0) sv[fi] = -INFINITY;
    }
    __syncthreads();
  }
}

// Top-k phase 2 + softmax + attention + pred (single block).
__global__ __launch_bounds__(256) void k_attn(
    const float* __restrict__ candV, const int* __restrict__ candI,
    const float* __restrict__ hs, const float* __restrict__ qh,
    const float* __restrict__ Ws, const float* __restrict__ bs,
    float* __restrict__ out) {
  __shared__ float sv[kNC];
  __shared__ float rv[4];
  __shared__ int ri[4];
  __shared__ float topv[kK];
  __shared__ int topi[kK];
  __shared__ float w[kK];
  __shared__ float red[256];
  const int tid = threadIdx.x;
  for (int i = tid; i < kNC; i += 256) sv[i] = candV[i];
  __syncthreads();
  for (int k = 0; k < kK; ++k) {
    float bv = -INFINITY; int bi = -1;
    for (int i = tid; i < kNC; i += 256) {
      float v = sv[i];
      if (v > bv) { bv = v; bi = i; }
    }
#pragma unroll
    for (int off = 32; off; off >>= 1) {
      float ov = __shfl_xor(bv, off);
      int   oi = __shfl_xor(bi, off);
      if (ov > bv || (ov == bv && oi != -1 && (bi == -1 || oi < bi))) { bv = ov; bi = oi; }
    }
    if ((tid & 63) == 0) { rv[tid >> 6] = bv; ri[tid >> 6] = bi; }
    __syncthreads();
    if (tid == 0) {
      float fv = rv[0]; int fi = ri[0];
      for (int j = 1; j < 4; ++j)
        if (rv[j] > fv || (rv[j] == fv && ri[j] != -1 && (fi == -1 || ri[j] < fi))) {
          fv = rv[j]; fi = ri[j];
        }
      topv[k] = fv;
      topi[k] = candI[fi];
      sv[fi] = -INFINITY;
    }
    __syncthreads();
  }
  if (tid == 0) {
    float m = topv[0];
    for (int j = 1; j < kK; ++j) m = fmaxf(m, topv[j]);
    float s = 0.f;
    for (int j = 0; j < kK; ++j) { w[j] = expf(topv[j] - m); s += w[j]; }
    float inv = 1.f / s;
    for (int j = 0; j < kK; ++j) w[j] *= inv;
  }
  __syncthreads();
  float a = 0.f;
#pragma unroll
  for (int j = 0; j < kK; ++j) a += w[j] * hs[(size_t)topi[j] * kH + tid];
  red[tid] = Ws[tid] * qh[tid] + Ws[kQ + tid] * a;
  __syncthreads();
  for (int s = 128; s; s >>= 1) {
    if (tid < s) red[tid] += red[tid + s];
    __syncthreads();
  }
  if (tid == 0) out[0] = red[0] + bs[0];
}

extern "C" void kernel_launch(void* const* d_in, const int* in_sizes, int n_in,
                              void* d_out, int out_size, void* d_ws, size_t ws_size,
                              hipStream_t stream) {
  const float* qh    = (const float*)d_in[0];
  const float* score = (const float*)d_in[1];
  const float* qs    = (const float*)d_in[2];
  const float* hs    = (const float*)d_in[3];
  const float* Wih   = (const float*)d_in[4];
  const float* Whh   = (const float*)d_in[5];
  const float* bih   = (const float*)d_in[6];
  const float* bhh   = (const float*)d_in[7];
  const float* Ws    = (const float*)d_in[8];
  const float* bs    = (const float*)d_in[9];
  float* out = (float*)d_out;

  const bool useWs = ws_size >= kScratchFloats * sizeof(float);
  // Fallback: scratch at start of the hs_new output region; consumers all run
  // before k_copy (launched last) overwrites that region.
  float* S = useWs ? (float*)d_ws : (out + 1 + (size_t)(kT + 1) * kQ);
  float* alpha = S;                         // kT
  float* candV = S + kT;                    // kNC
  int*   candI = (int*)(candV + kNC);       // kNC
  float* gi    = candV + 2 * kNC;           // 768
  float* gh    = gi + kGruRows;             // 768
  float* hnewS = gh + kGruRows;             // 256
  // Fallback: hnew computed straight into its final output row (the capped
  // copy never touches it).
  float* hnew  = useWs ? hnewS : (out + 1 + kC);

  hipLaunchKernelGGL(k_gru1, dim3(kGruBlocks), dim3(256), 0, stream,
                     Wih, Whh, bih, bhh, qh, hs, score, gi, gh);
  hipLaunchKernelGGL(k_gru2, dim3(1), dim3(256), 0, stream,
                     gi, gh, hs, hnew, out, useWs ? 0 : 1);
  hipLaunchKernelGGL(k_alpha, dim3(2048), dim3(256), 0, stream,
                     qs, qh, alpha);
  hipLaunchKernelGGL(k_topk1, dim3(kNB1), dim3(256), 0, stream,
                     alpha, candV, candI);
  hipLaunchKernelGGL(k_attn, dim3(1), dim3(256), 0, stream,
                     candV, candI, hs, qh, Ws, bs, out);
  hipLaunchKernelGGL(k_copy, dim3(2048), dim3(256), 0, stream,
                     qs, hs, qh, hnew, out,
                     useWs ? kEndFast : kEndFall, useWs ? 1 : 0);
}

// Round 7
// 616.989 us; speedup vs baseline: 1.4703x; 1.1644x over previous
//
#include <hip/hip_runtime.h>
#include <math.h>

// Problem constants (fixed by the reference)
constexpr int kT = 500000;     // history length
constexpr int kQ = 256;        // feature size
constexpr int kH = 256;        // hidden size
constexpr int kK = 32;         // attn_k
constexpr int kNB1 = 256;      // phase-1 top-k blocks
constexpr int kCHUNK = (kT + kNB1 - 1) / kNB1;  // 1954
constexpr int kNC = kNB1 * kK; // 8192 merge candidates
constexpr int kGruRows = 3 * kH;              // 768
constexpr int kGruBlocks = kGruRows / 4;      // 192 (4 waves/block, 1 row/wave)

typedef float f4  __attribute__((ext_vector_type(4)));
typedef float f4u __attribute__((ext_vector_type(4), aligned(4)));

// Nontemporal helpers: bypass cache allocation on the bulk streams so the
// write stream does not evict the read stream's lines in L2/L3.
__device__ __forceinline__ f4 nt_load4(const f4* p) {
  return __builtin_nontemporal_load(p);
}
__device__ __forceinline__ void nt_store4u(float* p, f4 v) {
  __builtin_nontemporal_store(v, (f4u*)p);
}

// Scratch floats: alpha kT + candV kNC + candI kNC + gi/gh 2*768
constexpr size_t kScratchFloats = (size_t)kT + 2 * kNC + 2 * kGruRows;

// ---------------------------------------------------------------------------
// Big fused copy (identical structure to the 593us R2 kernel; ONLY change is
// nontemporal load/store on the bulk streams): qs -> out rows [0,kT] with
// alpha = qs @ ques_h on the fly; optionally hs -> hs_new rows.
__global__ __launch_bounds__(256) void k_bigcopy(
    const float* __restrict__ qs, const float* __restrict__ hs,
    const float* __restrict__ qh, float* __restrict__ out,
    float* __restrict__ alpha, int doHs) {
  const int lane = threadIdx.x & 63;
  const int wid  = (int)((blockIdx.x * blockDim.x + threadIdx.x) >> 6);
  const int nw   = (int)((gridDim.x * blockDim.x) >> 6);
  const f4 q4 = ((const f4*)qh)[lane];
  const int totalRows = doHs ? (2 * kT + 1) : (kT + 1);
  for (int t = wid; t < totalRows; t += nw) {
    if (t <= kT) {
      const f4* src = (t < kT) ? (const f4*)(qs + (size_t)t * kQ)
                               : (const f4*)qh;
      f4 v = nt_load4(src + lane);
      nt_store4u(out + 1 + (size_t)t * kQ + lane * 4, v);
      if (t < kT) {
        float d = v.x * q4.x + v.y * q4.y + v.z * q4.z + v.w * q4.w;
#pragma unroll
        for (int off = 32; off; off >>= 1) d += __shfl_xor(d, off);
        if (lane == 0) alpha[t] = d;  // cached store: topk re-reads it
      }
    } else {
      const int r = t - (kT + 1);
      f4 v = nt_load4((const f4*)(hs + (size_t)r * kH) + lane);
      nt_store4u(out + 1 + (size_t)(kT + 1) * kQ + (size_t)r * kH + lane * 4, v);
    }
  }
}

// Standalone hs copy for the fallback (scratch-in-output) path; runs LAST.
__global__ __launch_bounds__(256) void k_copy_hs(
    const float* __restrict__ hs, float* __restrict__ out) {
  const size_t i      = (size_t)blockIdx.x * blockDim.x + threadIdx.x;
  const size_t stride = (size_t)gridDim.x * blockDim.x;
  float* base = out + 1 + (size_t)(kT + 1) * kQ;
  const f4* src = (const f4*)hs;
  const size_t nv = (size_t)kT * (kH / 4);
  for (size_t v = i; v < nv; v += stride) {
    nt_store4u(base + v * 4, nt_load4(src + v));
  }
}

// ---------------------------------------------------------------------------
// Fused: blocks [0,kNB1) do per-chunk top-32 of alpha; blocks [kNB1, +192) do
// the GRU matvecs (1 row per wave, 4 waves/block).
__global__ __launch_bounds__(256) void k_topk_gru(
    const float* __restrict__ alpha, float* __restrict__ candV,
    int* __restrict__ candI,
    const float* __restrict__ Wih, const float* __restrict__ Whh,
    const float* __restrict__ bih, const float* __restrict__ bhh,
    const float* __restrict__ qh, const float* __restrict__ hs,
    const float* __restrict__ score, float* __restrict__ gi,
    float* __restrict__ gh) {
  const int tid = threadIdx.x;
  if (blockIdx.x >= kNB1) {
    const int lane = tid & 63;
    const int r = (blockIdx.x - kNB1) * 4 + (tid >> 6);
    const int off = (score[0] >= 0.5f) ? 0 : kQ;  // x = [qh*ge, qh*(1-ge)]
    const float* hprev = hs + (size_t)(kT - 1) * kH;
    f4 q4 = ((const f4*)qh)[lane];
    f4 h4 = ((const f4*)hprev)[lane];
    f4 wi = ((const f4*)(Wih + (size_t)r * (2 * kQ) + off))[lane];
    f4 wh = ((const f4*)(Whh + (size_t)r * kH))[lane];
    float di = wi.x * q4.x + wi.y * q4.y + wi.z * q4.z + wi.w * q4.w;
    float dh = wh.x * h4.x + wh.y * h4.y + wh.z * h4.z + wh.w * h4.w;
#pragma unroll
    for (int o = 32; o; o >>= 1) {
      di += __shfl_xor(di, o);
      dh += __shfl_xor(dh, o);
    }
    if (lane == 0) {
      gi[r] = di + bih[r];
      gh[r] = dh + bhh[r];
    }
    return;
  }
  __shared__ float sv[kCHUNK];
  __shared__ float rv[4];
  __shared__ int ri[4];
  const int base = blockIdx.x * kCHUNK;
  for (int i = tid; i < kCHUNK; i += 256) {
    int g = base + i;
    sv[i] = (g < kT) ? alpha[g] : -INFINITY;
  }
  __syncthreads();
  for (int k = 0; k < kK; ++k) {
    float bv = -INFINITY; int bi = -1;
    for (int i = tid; i < kCHUNK; i += 256) {
      float v = sv[i];
      if (v > bv) { bv = v; bi = i; }
    }
#pragma unroll
    for (int off = 32; off; off >>= 1) {
      float ov = __shfl_xor(bv, off);
      int   oi = __shfl_xor(bi, off);
      if (ov > bv || (ov == bv && oi != -1 && (bi == -1 || oi < bi))) { bv = ov; bi = oi; }
    }
    if ((tid & 63) == 0) { rv[tid >> 6] = bv; ri[tid >> 6] = bi; }
    __syncthreads();
    if (tid == 0) {
      float fv = rv[0]; int fi = ri[0];
      for (int j = 1; j < 4; ++j)
        if (rv[j] > fv || (rv[j] == fv && ri[j] != -1 && (fi == -1 || ri[j] < fi))) {
          fv = rv[j]; fi = ri[j];
        }
      candV[blockIdx.x * kK + k] = fv;
      candI[blockIdx.x * kK + k] = (fi >= 0) ? (base + fi) : 0;
      if (fi >= 0) sv[fi] = -INFINITY;
    }
    __syncthreads();
  }
}

// ---------------------------------------------------------------------------
// Fused: block 0 = candidate merge + softmax + attn + pred; block 1 = GRU
// gates + write hs_new row kT.
__global__ __launch_bounds__(256) void k_attn_gru2(
    const float* __restrict__ candV, const int* __restrict__ candI,
    const float* __restrict__ hs, const float* __restrict__ qh,
    const float* __restrict__ Ws, const float* __restrict__ bs,
    const float* __restrict__ gi, const float* __restrict__ gh,
    float* __restrict__ out) {
  const int tid = threadIdx.x;
  if (blockIdx.x == 1) {
    const float* hprev = hs + (size_t)(kT - 1) * kH;
    float rr = 1.f / (1.f + expf(-(gi[tid] + gh[tid])));
    float z  = 1.f / (1.f + expf(-(gi[kH + tid] + gh[kH + tid])));
    float n  = tanhf(gi[2 * kH + tid] + rr * gh[2 * kH + tid]);
    float hn = (1.f - z) * n + z * hprev[tid];
    out[1 + (size_t)(kT + 1) * kQ + (size_t)kT * kH + tid] = hn;
    return;
  }
  __shared__ float sv[kNC];
  __shared__ float rv[4];
  __shared__ int ri[4];
  __shared__ float topv[kK];
  __shared__ int topi[kK];
  __shared__ float w[kK];
  __shared__ float red[256];
  for (int i = tid; i < kNC; i += 256) sv[i] = candV[i];
  __syncthreads();
  for (int k = 0; k < kK; ++k) {
    float bv = -INFINITY; int bi = -1;
    for (int i = tid; i < kNC; i += 256) {
      float v = sv[i];
      if (v > bv) { bv = v; bi = i; }
    }
#pragma unroll
    for (int off = 32; off; off >>= 1) {
      float ov = __shfl_xor(bv, off);
      int   oi = __shfl_xor(bi, off);
      if (ov > bv || (ov == bv && oi != -1 && (bi == -1 || oi < bi))) { bv = ov; bi = oi; }
    }
    if ((tid & 63) == 0) { rv[tid >> 6] = bv; ri[tid >> 6] = bi; }
    __syncthreads();
    if (tid == 0) {
      float fv = rv[0]; int fi = ri[0];
      for (int j = 1; j < 4; ++j)
        if (rv[j] > fv || (rv[j] == fv && ri[j] != -1 && (fi == -1 || ri[j] < fi))) {
          fv = rv[j]; fi = ri[j];
        }
      topv[k] = fv;
      topi[k] = candI[fi];
      sv[fi] = -INFINITY;
    }
    __syncthreads();
  }
  if (tid == 0) {
    float m = topv[0];
    for (int j = 1; j < kK; ++j) m = fmaxf(m, topv[j]);
    float s = 0.f;
    for (int j = 0; j < kK; ++j) { w[j] = expf(topv[j] - m); s += w[j]; }
    float inv = 1.f / s;
    for (int j = 0; j < kK; ++j) w[j] *= inv;
  }
  __syncthreads();
  float a = 0.f;
#pragma unroll
  for (int j = 0; j < kK; ++j) a += w[j] * hs[(size_t)topi[j] * kH + tid];
  red[tid] = Ws[tid] * qh[tid] + Ws[kQ + tid] * a;
  __syncthreads();
  for (int s = 128; s; s >>= 1) {
    if (tid < s) red[tid] += red[tid + s];
    __syncthreads();
  }
  if (tid == 0) out[0] = red[0] + bs[0];
}

extern "C" void kernel_launch(void* const* d_in, const int* in_sizes, int n_in,
                              void* d_out, int out_size, void* d_ws, size_t ws_size,
                              hipStream_t stream) {
  const float* qh    = (const float*)d_in[0];
  const float* score = (const float*)d_in[1];
  const float* qs    = (const float*)d_in[2];
  const float* hs    = (const float*)d_in[3];
  const float* Wih   = (const float*)d_in[4];
  const float* Whh   = (const float*)d_in[5];
  const float* bih   = (const float*)d_in[6];
  const float* bhh   = (const float*)d_in[7];
  const float* Ws    = (const float*)d_in[8];
  const float* bs    = (const float*)d_in[9];
  float* out = (float*)d_out;

  const bool useWs = ws_size >= kScratchFloats * sizeof(float);
  // Fallback: scratch at start of hs_new output region, consumed before the
  // hs half of the copy overwrites it.
  float* S = useWs ? (float*)d_ws : (out + 1 + (size_t)(kT + 1) * kQ);
  float* alpha = S;                      // kT floats
  float* candV = S + kT;                 // kNC floats
  int*   candI = (int*)(S + kT + kNC);   // kNC ints
  float* gi    = S + kT + 2 * kNC;       // 768 floats
  float* gh    = gi + kGruRows;          // 768 floats

  if (useWs) {
    hipLaunchKernelGGL(k_bigcopy, dim3(2048), dim3(256), 0, stream,
                       qs, hs, qh, out, alpha, 1);
    hipLaunchKernelGGL(k_topk_gru, dim3(kNB1 + kGruBlocks), dim3(256), 0, stream,
                       alpha, candV, candI, Wih, Whh, bih, bhh, qh, hs, score,
                       gi, gh);
    hipLaunchKernelGGL(k_attn_gru2, dim3(2), dim3(256), 0, stream,
                       candV, candI, hs, qh, Ws, bs, gi, gh, out);
  } else {
    hipLaunchKernelGGL(k_bigcopy, dim3(2048), dim3(256), 0, stream,
                       qs, hs, qh, out, alpha, 0);
    hipLaunchKernelGGL(k_topk_gru, dim3(kNB1 + kGruBlocks), dim3(256), 0, stream,
                       alpha, candV, candI, Wih, Whh, bih, bhh, qh, hs, score,
                       gi, gh);
    hipLaunchKernelGGL(k_attn_gru2, dim3(2), dim3(256), 0, stream,
                       candV, candI, hs, qh, Ws, bs, gi, gh, out);
    hipLaunchKernelGGL(k_copy_hs, dim3(2048), dim3(256), 0, stream,
                       hs, out);
  }
}